// Round 3
// baseline (367.251 us; speedup 1.0000x reference)
//
#include <hip/hip_runtime.h>
#include <hip/hip_bf16.h>
#include <math.h>

#define IN_D 128
#define HID_D 128
#define OUT_D 64

typedef __attribute__((ext_vector_type(8))) short bf16x8;
typedef __attribute__((ext_vector_type(4))) float f32x4;

__device__ __forceinline__ unsigned short f2bf(float f) {
    unsigned u = __float_as_uint(f);
    u += 0x7fffu + ((u >> 16) & 1u);   // RTNE
    return (unsigned short)(u >> 16);
}
__device__ __forceinline__ float bf2f(unsigned short h) {
    return __uint_as_float(((unsigned)h) << 16);
}

// ---- edge count + (fused, independent) weight prep fp32->bf16 ----
__global__ __launch_bounds__(256) void k_count(const int* __restrict__ dst_idx,
                                               int* __restrict__ deg, int E,
                                               const float* __restrict__ W1, const float* __restrict__ F1,
                                               const float* __restrict__ W2, const float* __restrict__ F2,
                                               const float* __restrict__ Wp,
                                               unsigned short* __restrict__ wc1,
                                               unsigned short* __restrict__ wc2,
                                               unsigned short* __restrict__ wpb) {
    int e = blockIdx.x * 256 + threadIdx.x;
    if (e < E) atomicAdd(&deg[dst_idx[e]], 1);
    // weight prep: [W;Fg;Fb] stacking for both layers + Wp, fp32->bf16
    const int NW = HID_D * IN_D;          // 16384
    const int NC = 3 * NW;                // 49152
    const int NP = OUT_D * HID_D;         // 8192
    int i = e;
    if (i < NC) {
        wc1[i] = f2bf(i < NW ? W1[i] : F1[i - NW]);
    } else if (i < 2 * NC) {
        int j = i - NC;
        wc2[j] = f2bf(j < NW ? W2[j] : F2[j - NW]);
    } else if (i < 2 * NC + NP) {
        int j = i - 2 * NC;
        wpb[j] = f2bf(Wp[j]);
    }
}

// ---- segment allocation: contiguous range per node, order arbitrary ----
// wave-scan of deg + one atomicAdd per wave on a global counter. No prefix scan.
__global__ __launch_bounds__(256) void k_alloc(const int* __restrict__ deg,
                                               int* __restrict__ counter,
                                               int* __restrict__ offs,
                                               int* __restrict__ cursor, int n) {
    int tid = threadIdx.x, lane = tid & 63;
    int i = blockIdx.x * 256 + tid;
    int v = (i < n) ? deg[i] : 0;
    int x = v;
    #pragma unroll
    for (int d = 1; d < 64; d <<= 1) {
        int y = __shfl_up(x, d);
        if (lane >= d) x += y;
    }
    int wbase = 0;
    if (lane == 63) wbase = atomicAdd(counter, x);
    wbase = __shfl(wbase, 63);
    if (i < n) {
        int o = wbase + x - v;
        offs[i] = o;
        cursor[i] = o;
    }
}

__global__ __launch_bounds__(256) void k_fill(const int* __restrict__ src_idx,
                                              const int* __restrict__ dst_idx,
                                              int* __restrict__ cursor,
                                              int* __restrict__ elist, int E) {
    int e = blockIdx.x * 256 + threadIdx.x;
    if (e < E) {
        int pos = atomicAdd(&cursor[dst_idx[e]], 1);
        elist[pos] = src_idx[e];
    }
}

// ---- fused GEMM + FiLM, 32 rows/block (lower VGPR -> higher occupancy) ----
__device__ __forceinline__ bf16x8 load_frag(const unsigned short* p) {
    return *(const bf16x8*)p;
}
__device__ __forceinline__ bf16x8 load_frag(const float* p) {
    float4 u = ((const float4*)p)[0];
    float4 w = ((const float4*)p)[1];
    bf16x8 r;
    r[0] = (short)f2bf(u.x); r[1] = (short)f2bf(u.y);
    r[2] = (short)f2bf(u.z); r[3] = (short)f2bf(u.w);
    r[4] = (short)f2bf(w.x); r[5] = (short)f2bf(w.y);
    r[6] = (short)f2bf(w.z); r[7] = (short)f2bf(w.w);
    return r;
}

// Wc = [W(128); Fgamma(128); Fbeta(128)] x 128 bf16 row-major.
// Block: 4 waves, 32 rows (2 row-tiles). Wave w owns m col-tiles {2w,2w+1}.
template <typename XT>
__global__ __launch_bounds__(256) void k_msg(const XT* __restrict__ X,
                                             const unsigned short* __restrict__ Wc,
                                             unsigned short* __restrict__ Msg, int n) {
    const int row0 = blockIdx.x << 5;
    const int wave = threadIdx.x >> 6;
    const int lane = threadIdx.x & 63;
    const int lr = lane & 15;
    const int quad = lane >> 4;

    bf16x8 a[2][4];   // [rowtile][kstep]
    #pragma unroll
    for (int rt = 0; rt < 2; rt++) {
        int r = row0 + rt * 16 + lr;
        if (r > n - 1) r = n - 1;
        const XT* xp = X + (size_t)r * IN_D + quad * 8;
        #pragma unroll
        for (int s = 0; s < 4; s++) a[rt][s] = load_frag(xp + 32 * s);
    }

    const int t0 = wave * 2;
    const int tidx[6] = {t0, t0 + 1, t0 + 8, t0 + 9, t0 + 16, t0 + 17};
    f32x4 acc[6][2];
    #pragma unroll
    for (int u = 0; u < 6; u++)
        #pragma unroll
        for (int rt = 0; rt < 2; rt++) acc[u][rt] = (f32x4){0.f, 0.f, 0.f, 0.f};

    #pragma unroll
    for (int s = 0; s < 4; s++) {
        #pragma unroll
        for (int u = 0; u < 6; u++) {
            const bf16x8 b = *(const bf16x8*)(Wc + (size_t)(16 * tidx[u] + lr) * IN_D + quad * 8 + 32 * s);
            #pragma unroll
            for (int rt = 0; rt < 2; rt++)
                acc[u][rt] = __builtin_amdgcn_mfma_f32_16x16x32_bf16(a[rt][s], b, acc[u][rt], 0, 0, 0);
        }
    }
    // FiLM: m=acc[0..1], gamma=acc[2..3], beta=acc[4..5]; identical (row,col) slots.
    #pragma unroll
    for (int u = 0; u < 2; u++) {
        #pragma unroll
        for (int rt = 0; rt < 2; rt++) {
            #pragma unroll
            for (int r = 0; r < 4; r++) {
                int row = row0 + rt * 16 + quad * 4 + r;
                if (row < n) {
                    float v = acc[2 + u][rt][r] * acc[u][rt][r] + acc[4 + u][rt][r];
                    v = v > 0.f ? v : 0.f;
                    Msg[(size_t)row * HID_D + 16 * (t0 + u) + lr] = f2bf(v);
                }
            }
        }
    }
}

// ---- CSR aggregate + LayerNorm (+ optional fused projection+sigmoid) ----
// 1 wave/node; quarter-wave (16 lanes x uint4 = 256B) per edge; 8 edges in flight.
template <bool FUSE_PROJ>
__global__ __launch_bounds__(256) void k_agg(const unsigned short* __restrict__ Msg,
                                             const int* __restrict__ elist,
                                             const int* __restrict__ offs,
                                             const int* __restrict__ deg,
                                             const float* __restrict__ gamma,
                                             const float* __restrict__ beta,
                                             unsigned short* __restrict__ Hout,
                                             const unsigned short* __restrict__ Wpb,
                                             const float* __restrict__ bp,
                                             float* __restrict__ out, int n) {
    __shared__ float hsh[4][128];
    const int wave = threadIdx.x >> 6;
    const int lane = threadIdx.x & 63;
    const int node = blockIdx.x * 4 + wave;
    if (node >= n) return;
    const int q = lane >> 4;      // quarter 0..3
    const int l = lane & 15;      // lane-in-quarter; owns cols l*8 .. l*8+7
    const int s0 = offs[node];
    const int s1 = s0 + deg[node];

    float a[8];
    #pragma unroll
    for (int k = 0; k < 8; k++) a[k] = 0.f;

#define ACC8(v) { a[0] += bf2f((unsigned short)((v).x & 0xffffu)); \
                  a[1] += bf2f((unsigned short)((v).x >> 16));     \
                  a[2] += bf2f((unsigned short)((v).y & 0xffffu)); \
                  a[3] += bf2f((unsigned short)((v).y >> 16));     \
                  a[4] += bf2f((unsigned short)((v).z & 0xffffu)); \
                  a[5] += bf2f((unsigned short)((v).z >> 16));     \
                  a[6] += bf2f((unsigned short)((v).w & 0xffffu)); \
                  a[7] += bf2f((unsigned short)((v).w >> 16)); }

    int i = s0;
    for (; i + 8 <= s1; i += 8) {
        int eA = elist[i + q];
        int eB = elist[i + 4 + q];
        uint4 vA = *(const uint4*)(Msg + (size_t)eA * HID_D + l * 8);
        uint4 vB = *(const uint4*)(Msg + (size_t)eB * HID_D + l * 8);
        ACC8(vA);
        ACC8(vB);
    }
    for (; i + 4 <= s1; i += 4) {
        int eA = elist[i + q];
        uint4 vA = *(const uint4*)(Msg + (size_t)eA * HID_D + l * 8);
        ACC8(vA);
    }
    int r = s1 - i;               // 0..3
    if (q < r) {
        int eA = elist[i + q];
        uint4 vA = *(const uint4*)(Msg + (size_t)eA * HID_D + l * 8);
        ACC8(vA);
    }
#undef ACC8

    // fold the 4 quarter partials: every lane ends with full column sums
    #pragma unroll
    for (int k = 0; k < 8; k++) {
        a[k] += __shfl_xor(a[k], 16);
        a[k] += __shfl_xor(a[k], 32);
    }
    float s = 0.f, sq = 0.f;
    #pragma unroll
    for (int k = 0; k < 8; k++) { s += a[k]; sq += a[k] * a[k]; }
    #pragma unroll
    for (int d = 8; d; d >>= 1) {
        s += __shfl_xor(s, d);
        sq += __shfl_xor(sq, d);
    }
    float mu = s * (1.f / 128.f);
    float var = sq * (1.f / 128.f) - mu * mu;
    float rs = rsqrtf(var + 1e-5f);

    float4 g0 = ((const float4*)gamma)[2 * l];
    float4 g1 = ((const float4*)gamma)[2 * l + 1];
    float4 b0 = ((const float4*)beta)[2 * l];
    float4 b1 = ((const float4*)beta)[2 * l + 1];
    float y[8];
    y[0] = (a[0] - mu) * rs * g0.x + b0.x;
    y[1] = (a[1] - mu) * rs * g0.y + b0.y;
    y[2] = (a[2] - mu) * rs * g0.z + b0.z;
    y[3] = (a[3] - mu) * rs * g0.w + b0.w;
    y[4] = (a[4] - mu) * rs * g1.x + b1.x;
    y[5] = (a[5] - mu) * rs * g1.y + b1.y;
    y[6] = (a[6] - mu) * rs * g1.z + b1.z;
    y[7] = (a[7] - mu) * rs * g1.w + b1.w;

    if (!FUSE_PROJ) {
        if (q == 0) {
            uint4 o;
            o.x = (unsigned)f2bf(y[0]) | ((unsigned)f2bf(y[1]) << 16);
            o.y = (unsigned)f2bf(y[2]) | ((unsigned)f2bf(y[3]) << 16);
            o.z = (unsigned)f2bf(y[4]) | ((unsigned)f2bf(y[5]) << 16);
            o.w = (unsigned)f2bf(y[6]) | ((unsigned)f2bf(y[7]) << 16);
            *(uint4*)(Hout + (size_t)node * HID_D + l * 8) = o;
        }
    } else {
        // stash h in this wave's LDS slice, then lane j computes out col j
        if (q == 0) {
            *(float4*)&hsh[wave][l * 8]     = (float4){y[0], y[1], y[2], y[3]};
            *(float4*)&hsh[wave][l * 8 + 4] = (float4){y[4], y[5], y[6], y[7]};
        }
        float accp = bp[lane];
        const unsigned short* wrow = Wpb + (size_t)lane * HID_D;
        #pragma unroll
        for (int c4 = 0; c4 < 32; c4++) {
            float4 hv = ((const float4*)hsh[wave])[c4];
            ushort4 wv = ((const ushort4*)wrow)[c4];
            accp += hv.x * bf2f(wv.x) + hv.y * bf2f(wv.y) +
                    hv.z * bf2f(wv.z) + hv.w * bf2f(wv.w);
        }
        out[(size_t)node * OUT_D + lane] = 1.f / (1.f + __expf(-accp));
    }
}

extern "C" void kernel_launch(void* const* d_in, const int* in_sizes, int n_in,
                              void* d_out, int out_size, void* d_ws, size_t ws_size,
                              hipStream_t stream) {
    const float* features = (const float*)d_in[0];
    const int* src = (const int*)d_in[1];
    const int* dst = (const int*)d_in[2];
    const float* W1 = (const float*)d_in[3];
    const float* F1 = (const float*)d_in[4];
    const float* g1 = (const float*)d_in[5];
    const float* b1 = (const float*)d_in[6];
    const float* W2 = (const float*)d_in[7];
    const float* F2 = (const float*)d_in[8];
    const float* g2 = (const float*)d_in[9];
    const float* b2 = (const float*)d_in[10];
    const float* Wp = (const float*)d_in[11];
    const float* bp = (const float*)d_in[12];

    const int N = in_sizes[0] / IN_D;   // 50000
    const int E = in_sizes[1];          // 600000
    float* out = (float*)d_out;

    char* p = (char*)d_ws;
    auto alloc = [&](size_t b) -> char* {
        char* r = p;
        p += (b + 255) & ~(size_t)255;
        return r;
    };
    unsigned short* buf0 = (unsigned short*)alloc((size_t)N * HID_D * 2);
    unsigned short* buf1 = (unsigned short*)alloc((size_t)N * HID_D * 2);
    unsigned short* wc1  = (unsigned short*)alloc((size_t)3 * HID_D * IN_D * 2);
    unsigned short* wc2  = (unsigned short*)alloc((size_t)3 * HID_D * HID_D * 2);
    unsigned short* wpb  = (unsigned short*)alloc((size_t)OUT_D * HID_D * 2);
    int* deg    = (int*)alloc((size_t)(N + 1) * 4);   // deg[N] is the alloc counter
    int* cursor = (int*)alloc((size_t)N * 4);
    int* offs   = (int*)alloc((size_t)N * 4);
    int* elist  = (int*)alloc((size_t)E * 4);

    const int eb = (E + 255) / 256;       // 2344 (also covers fused weight prep)
    const int nb = (N + 255) / 256;       // 196
    const int mb = (N + 31) / 32;         // 1563
    const int ab = (N + 3) / 4;           // 12500

    // CSR build: count(+prep) -> alloc (no prefix scan) -> fill
    hipMemsetAsync(deg, 0, (size_t)(N + 1) * 4, stream);
    k_count<<<eb, 256, 0, stream>>>(dst, deg, E, W1, F1, W2, F2, Wp, wc1, wc2, wpb);
    k_alloc<<<nb, 256, 0, stream>>>(deg, deg + N, offs, cursor, N);
    k_fill<<<eb, 256, 0, stream>>>(src, dst, cursor, elist, E);

    // layer 1 (reads fp32 features directly)
    k_msg<float><<<mb, 256, 0, stream>>>(features, wc1, buf1, N);
    k_agg<false><<<ab, 256, 0, stream>>>(buf1, elist, offs, deg, g1, b1, buf0,
                                         nullptr, nullptr, nullptr, N);
    // layer 2 + fused projection/sigmoid
    k_msg<unsigned short><<<mb, 256, 0, stream>>>(buf0, wc2, buf1, N);
    k_agg<true><<<ab, 256, 0, stream>>>(buf1, elist, offs, deg, g2, b2, nullptr,
                                        wpb, bp, out, N);
}

// Round 4
// 355.575 us; speedup vs baseline: 1.0328x; 1.0328x over previous
//
#include <hip/hip_runtime.h>
#include <hip/hip_bf16.h>
#include <math.h>

#define IN_D 128
#define HID_D 128
#define OUT_D 64

typedef __attribute__((ext_vector_type(8))) short bf16x8;
typedef __attribute__((ext_vector_type(4))) float f32x4;

__device__ __forceinline__ unsigned short f2bf(float f) {
    unsigned u = __float_as_uint(f);
    u += 0x7fffu + ((u >> 16) & 1u);   // RTNE
    return (unsigned short)(u >> 16);
}
__device__ __forceinline__ float bf2f(unsigned short h) {
    return __uint_as_float(((unsigned)h) << 16);
}

// ---- edge count + (fused, independent) weight prep fp32->bf16 ----
__global__ __launch_bounds__(256) void k_count(const int* __restrict__ dst_idx,
                                               int* __restrict__ deg, int E,
                                               const float* __restrict__ W1, const float* __restrict__ F1,
                                               const float* __restrict__ W2, const float* __restrict__ F2,
                                               const float* __restrict__ Wp,
                                               unsigned short* __restrict__ wc1,
                                               unsigned short* __restrict__ wc2,
                                               unsigned short* __restrict__ wpb) {
    int e = blockIdx.x * 256 + threadIdx.x;
    if (e < E) atomicAdd(&deg[dst_idx[e]], 1);
    const int NW = HID_D * IN_D;          // 16384
    const int NC = 3 * NW;                // 49152
    const int NP = OUT_D * HID_D;         // 8192
    int i = e;
    if (i < NC) {
        wc1[i] = f2bf(i < NW ? W1[i] : F1[i - NW]);
    } else if (i < 2 * NC) {
        int j = i - NC;
        wc2[j] = f2bf(j < NW ? W2[j] : F2[j - NW]);
    } else if (i < 2 * NC + NP) {
        int j = i - 2 * NC;
        wpb[j] = f2bf(Wp[j]);
    }
}

// ---- segment allocation: contiguous range per node, order arbitrary ----
__global__ __launch_bounds__(256) void k_alloc(const int* __restrict__ deg,
                                               int* __restrict__ counter,
                                               int* __restrict__ offs,
                                               int* __restrict__ cursor, int n) {
    int tid = threadIdx.x, lane = tid & 63;
    int i = blockIdx.x * 256 + tid;
    int v = (i < n) ? deg[i] : 0;
    int x = v;
    #pragma unroll
    for (int d = 1; d < 64; d <<= 1) {
        int y = __shfl_up(x, d);
        if (lane >= d) x += y;
    }
    int wbase = 0;
    if (lane == 63) wbase = atomicAdd(counter, x);
    wbase = __shfl(wbase, 63);
    if (i < n) {
        int o = wbase + x - v;
        offs[i] = o;
        cursor[i] = o;
    }
}

__global__ __launch_bounds__(256) void k_fill(const int* __restrict__ src_idx,
                                              const int* __restrict__ dst_idx,
                                              int* __restrict__ cursor,
                                              int* __restrict__ elist, int E) {
    int e = blockIdx.x * 256 + threadIdx.x;
    if (e < E) {
        int pos = atomicAdd(&cursor[dst_idx[e]], 1);
        elist[pos] = src_idx[e];
    }
}

// ---- fused GEMM + FiLM, 64 rows/block ----
__device__ __forceinline__ bf16x8 load_frag(const unsigned short* p) {
    return *(const bf16x8*)p;
}
__device__ __forceinline__ bf16x8 load_frag(const float* p) {
    float4 u = ((const float4*)p)[0];
    float4 w = ((const float4*)p)[1];
    bf16x8 r;
    r[0] = (short)f2bf(u.x); r[1] = (short)f2bf(u.y);
    r[2] = (short)f2bf(u.z); r[3] = (short)f2bf(u.w);
    r[4] = (short)f2bf(w.x); r[5] = (short)f2bf(w.y);
    r[6] = (short)f2bf(w.z); r[7] = (short)f2bf(w.w);
    return r;
}

// Wc = [W(128); Fgamma(128); Fbeta(128)] x 128 bf16 row-major.
// Block: 4 waves, 64 rows (4 row-tiles). Wave w owns m col-tiles {2w,2w+1}.
template <typename XT>
__global__ __launch_bounds__(256, 2) void k_msg(const XT* __restrict__ X,
                                                const unsigned short* __restrict__ Wc,
                                                unsigned short* __restrict__ Msg, int n) {
    const int row0 = blockIdx.x << 6;
    const int wave = threadIdx.x >> 6;
    const int lane = threadIdx.x & 63;
    const int lr = lane & 15;
    const int quad = lane >> 4;

    bf16x8 a[4][4];   // [rowtile][kstep]
    #pragma unroll
    for (int rt = 0; rt < 4; rt++) {
        int r = row0 + rt * 16 + lr;
        if (r > n - 1) r = n - 1;
        const XT* xp = X + (size_t)r * IN_D + quad * 8;
        #pragma unroll
        for (int s = 0; s < 4; s++) a[rt][s] = load_frag(xp + 32 * s);
    }

    const int t0 = wave * 2;
    const int tidx[6] = {t0, t0 + 1, t0 + 8, t0 + 9, t0 + 16, t0 + 17};
    f32x4 acc[6][4];
    #pragma unroll
    for (int u = 0; u < 6; u++)
        #pragma unroll
        for (int rt = 0; rt < 4; rt++) acc[u][rt] = (f32x4){0.f, 0.f, 0.f, 0.f};

    #pragma unroll
    for (int s = 0; s < 4; s++) {
        #pragma unroll
        for (int u = 0; u < 6; u++) {
            const bf16x8 b = *(const bf16x8*)(Wc + (size_t)(16 * tidx[u] + lr) * IN_D + quad * 8 + 32 * s);
            #pragma unroll
            for (int rt = 0; rt < 4; rt++)
                acc[u][rt] = __builtin_amdgcn_mfma_f32_16x16x32_bf16(a[rt][s], b, acc[u][rt], 0, 0, 0);
        }
    }
    // FiLM: m=acc[0..1], gamma=acc[2..3], beta=acc[4..5]; identical (row,col) slots.
    #pragma unroll
    for (int u = 0; u < 2; u++) {
        #pragma unroll
        for (int rt = 0; rt < 4; rt++) {
            #pragma unroll
            for (int r = 0; r < 4; r++) {
                int row = row0 + rt * 16 + quad * 4 + r;
                if (row < n) {
                    float v = acc[2 + u][rt][r] * acc[u][rt][r] + acc[4 + u][rt][r];
                    v = v > 0.f ? v : 0.f;
                    Msg[(size_t)row * HID_D + 16 * (t0 + u) + lr] = f2bf(v);
                }
            }
        }
    }
}

// ---- CSR aggregate + LayerNorm (+ optional fused projection+sigmoid) ----
// 1 wave/node. Round-1 memory shape: 64 lanes x 4B = one coalesced 256B row
// per load instruction; 4 independent accumulator streams over consecutive
// edges so >=4 gathers are in flight while staying a simple pipelineable loop.
template <bool FUSE_PROJ>
__global__ __launch_bounds__(256) void k_agg(const unsigned short* __restrict__ Msg,
                                             const int* __restrict__ elist,
                                             const int* __restrict__ offs,
                                             const int* __restrict__ deg,
                                             const float* __restrict__ gamma,
                                             const float* __restrict__ beta,
                                             unsigned short* __restrict__ Hout,
                                             const unsigned short* __restrict__ Wpb,
                                             const float* __restrict__ bp,
                                             float* __restrict__ out, int n) {
    __shared__ float hsh[4][128];
    const int wave = threadIdx.x >> 6;
    const int lane = threadIdx.x & 63;
    const int node = blockIdx.x * 4 + wave;
    if (node >= n) return;
    const int s0 = offs[node];
    const int s1 = s0 + deg[node];
    const unsigned short* mp = Msg + 2 * lane;

    float a0 = 0.f, a1 = 0.f, b0 = 0.f, b1 = 0.f;
    float c0 = 0.f, c1 = 0.f, d0 = 0.f, d1 = 0.f;

    int i = s0;
    for (; i + 4 <= s1; i += 4) {
        int eA = elist[i],     eB = elist[i + 1];
        int eC = elist[i + 2], eD = elist[i + 3];
        unsigned vA = *(const unsigned*)(mp + (size_t)eA * HID_D);
        unsigned vB = *(const unsigned*)(mp + (size_t)eB * HID_D);
        unsigned vC = *(const unsigned*)(mp + (size_t)eC * HID_D);
        unsigned vD = *(const unsigned*)(mp + (size_t)eD * HID_D);
        a0 += bf2f((unsigned short)(vA & 0xffffu)); a1 += bf2f((unsigned short)(vA >> 16));
        b0 += bf2f((unsigned short)(vB & 0xffffu)); b1 += bf2f((unsigned short)(vB >> 16));
        c0 += bf2f((unsigned short)(vC & 0xffffu)); c1 += bf2f((unsigned short)(vC >> 16));
        d0 += bf2f((unsigned short)(vD & 0xffffu)); d1 += bf2f((unsigned short)(vD >> 16));
    }
    for (; i < s1; i++) {
        unsigned vA = *(const unsigned*)(mp + (size_t)elist[i] * HID_D);
        a0 += bf2f((unsigned short)(vA & 0xffffu)); a1 += bf2f((unsigned short)(vA >> 16));
    }
    a0 += b0 + c0 + d0;
    a1 += b1 + c1 + d1;

    float s = a0 + a1;
    float sq = a0 * a0 + a1 * a1;
    #pragma unroll
    for (int d = 32; d; d >>= 1) {
        s += __shfl_xor(s, d);
        sq += __shfl_xor(sq, d);
    }
    float mu = s * (1.f / 128.f);
    float var = sq * (1.f / 128.f) - mu * mu;
    float rs = rsqrtf(var + 1e-5f);
    int c = 2 * lane;
    float y0 = (a0 - mu) * rs * gamma[c] + beta[c];
    float y1 = (a1 - mu) * rs * gamma[c + 1] + beta[c + 1];

    if (!FUSE_PROJ) {
        unsigned o = (unsigned)f2bf(y0) | ((unsigned)f2bf(y1) << 16);
        *(unsigned*)(Hout + (size_t)node * HID_D + c) = o;
    } else {
        // stash h in this wave's LDS slice, then lane j computes out col j
        *(float2*)&hsh[wave][c] = (float2){y0, y1};
        float accp = bp[lane];
        const unsigned short* wrow = Wpb + (size_t)lane * HID_D;
        #pragma unroll
        for (int c4 = 0; c4 < 32; c4++) {
            float4 hv = ((const float4*)hsh[wave])[c4];
            ushort4 wv = ((const ushort4*)wrow)[c4];
            accp += hv.x * bf2f(wv.x) + hv.y * bf2f(wv.y) +
                    hv.z * bf2f(wv.z) + hv.w * bf2f(wv.w);
        }
        out[(size_t)node * OUT_D + lane] = 1.f / (1.f + __expf(-accp));
    }
}

extern "C" void kernel_launch(void* const* d_in, const int* in_sizes, int n_in,
                              void* d_out, int out_size, void* d_ws, size_t ws_size,
                              hipStream_t stream) {
    const float* features = (const float*)d_in[0];
    const int* src = (const int*)d_in[1];
    const int* dst = (const int*)d_in[2];
    const float* W1 = (const float*)d_in[3];
    const float* F1 = (const float*)d_in[4];
    const float* g1 = (const float*)d_in[5];
    const float* b1 = (const float*)d_in[6];
    const float* W2 = (const float*)d_in[7];
    const float* F2 = (const float*)d_in[8];
    const float* g2 = (const float*)d_in[9];
    const float* b2 = (const float*)d_in[10];
    const float* Wp = (const float*)d_in[11];
    const float* bp = (const float*)d_in[12];

    const int N = in_sizes[0] / IN_D;   // 50000
    const int E = in_sizes[1];          // 600000
    float* out = (float*)d_out;

    char* p = (char*)d_ws;
    auto alloc = [&](size_t b) -> char* {
        char* r = p;
        p += (b + 255) & ~(size_t)255;
        return r;
    };
    unsigned short* buf0 = (unsigned short*)alloc((size_t)N * HID_D * 2);
    unsigned short* buf1 = (unsigned short*)alloc((size_t)N * HID_D * 2);
    unsigned short* wc1  = (unsigned short*)alloc((size_t)3 * HID_D * IN_D * 2);
    unsigned short* wc2  = (unsigned short*)alloc((size_t)3 * HID_D * HID_D * 2);
    unsigned short* wpb  = (unsigned short*)alloc((size_t)OUT_D * HID_D * 2);
    int* deg    = (int*)alloc((size_t)(N + 1) * 4);   // deg[N] is the alloc counter
    int* cursor = (int*)alloc((size_t)N * 4);
    int* offs   = (int*)alloc((size_t)N * 4);
    int* elist  = (int*)alloc((size_t)E * 4);

    const int eb = (E + 255) / 256;       // 2344 (also covers fused weight prep)
    const int nb = (N + 255) / 256;       // 196
    const int mb = (N + 63) / 64;         // 782
    const int ab = (N + 3) / 4;           // 12500

    // CSR build: count(+prep) -> alloc (no prefix scan) -> fill
    hipMemsetAsync(deg, 0, (size_t)(N + 1) * 4, stream);
    k_count<<<eb, 256, 0, stream>>>(dst, deg, E, W1, F1, W2, F2, Wp, wc1, wc2, wpb);
    k_alloc<<<nb, 256, 0, stream>>>(deg, deg + N, offs, cursor, N);
    k_fill<<<eb, 256, 0, stream>>>(src, dst, cursor, elist, E);

    // layer 1 (reads fp32 features directly)
    k_msg<float><<<mb, 256, 0, stream>>>(features, wc1, buf1, N);
    k_agg<false><<<ab, 256, 0, stream>>>(buf1, elist, offs, deg, g1, b1, buf0,
                                         nullptr, nullptr, nullptr, N);
    // layer 2 + fused projection/sigmoid
    k_msg<unsigned short><<<mb, 256, 0, stream>>>(buf0, wc2, buf1, N);
    k_agg<true><<<ab, 256, 0, stream>>>(buf1, elist, offs, deg, g2, b2, nullptr,
                                        wpb, bp, out, N);
}

// Round 5
// 353.285 us; speedup vs baseline: 1.0395x; 1.0065x over previous
//
#include <hip/hip_runtime.h>
#include <hip/hip_bf16.h>
#include <math.h>

#define IN_D 128
#define HID_D 128
#define OUT_D 64

typedef __attribute__((ext_vector_type(8))) short bf16x8;
typedef __attribute__((ext_vector_type(4))) float f32x4;

__device__ __forceinline__ unsigned short f2bf(float f) {
    unsigned u = __float_as_uint(f);
    u += 0x7fffu + ((u >> 16) & 1u);   // RTNE
    return (unsigned short)(u >> 16);
}
__device__ __forceinline__ float bf2f(unsigned short h) {
    return __uint_as_float(((unsigned)h) << 16);
}

// ---- edge count + (fused, independent) weight prep fp32->bf16 ----
__global__ __launch_bounds__(256) void k_count(const int* __restrict__ dst_idx,
                                               int* __restrict__ deg, int E,
                                               const float* __restrict__ W1, const float* __restrict__ F1,
                                               const float* __restrict__ W2, const float* __restrict__ F2,
                                               const float* __restrict__ Wp,
                                               unsigned short* __restrict__ wc1,
                                               unsigned short* __restrict__ wc2,
                                               unsigned short* __restrict__ wpb) {
    int e = blockIdx.x * 256 + threadIdx.x;
    if (e < E) atomicAdd(&deg[dst_idx[e]], 1);
    const int NW = HID_D * IN_D;          // 16384
    const int NC = 3 * NW;                // 49152
    const int NP = OUT_D * HID_D;         // 8192
    int i = e;
    if (i < NC) {
        wc1[i] = f2bf(i < NW ? W1[i] : F1[i - NW]);
    } else if (i < 2 * NC) {
        int j = i - NC;
        wc2[j] = f2bf(j < NW ? W2[j] : F2[j - NW]);
    } else if (i < 2 * NC + NP) {
        int j = i - 2 * NC;
        wpb[j] = f2bf(Wp[j]);
    }
}

// ---- CSR build: 3-kernel prefix scan (round-2 known-good) ----
__global__ __launch_bounds__(256) void k_part(const int* __restrict__ deg,
                                              int* __restrict__ part, int n) {
    int t = threadIdx.x, lane = t & 63, w = t >> 6;
    int i = blockIdx.x * 256 + t;
    int v = (i < n) ? deg[i] : 0;
    #pragma unroll
    for (int d = 32; d; d >>= 1) v += __shfl_xor(v, d);
    __shared__ int ws[4];
    if (lane == 0) ws[w] = v;
    __syncthreads();
    if (t == 0) part[blockIdx.x] = ws[0] + ws[1] + ws[2] + ws[3];
}

// single block, nb <= 256: exclusive scan of part -> base; total -> offs[n]
__global__ __launch_bounds__(256) void k_mid(const int* __restrict__ part,
                                             int* __restrict__ base,
                                             int* __restrict__ offs, int nb, int n) {
    int t = threadIdx.x, lane = t & 63, w = t >> 6;
    int v = (t < nb) ? part[t] : 0;
    int x = v;
    #pragma unroll
    for (int d = 1; d < 64; d <<= 1) {
        int y = __shfl_up(x, d);
        if (lane >= d) x += y;
    }
    __shared__ int wsum[4], woff[4];
    if (lane == 63) wsum[w] = x;
    __syncthreads();
    if (t == 0) {
        int run = 0;
        #pragma unroll
        for (int k = 0; k < 4; k++) { int s = wsum[k]; woff[k] = run; run += s; }
        offs[n] = run;
    }
    __syncthreads();
    if (t < nb) base[t] = woff[w] + x - v;
}

__global__ __launch_bounds__(256) void k_scatter(const int* __restrict__ deg,
                                                 const int* __restrict__ base,
                                                 int* __restrict__ offs,
                                                 int* __restrict__ cursor, int n) {
    int t = threadIdx.x, lane = t & 63, w = t >> 6;
    int i = blockIdx.x * 256 + t;
    int v = (i < n) ? deg[i] : 0;
    int x = v;
    #pragma unroll
    for (int d = 1; d < 64; d <<= 1) {
        int y = __shfl_up(x, d);
        if (lane >= d) x += y;
    }
    __shared__ int wsum[4], woff[4];
    if (lane == 63) wsum[w] = x;
    __syncthreads();
    if (t == 0) {
        int run = base[blockIdx.x];
        #pragma unroll
        for (int k = 0; k < 4; k++) { int s = wsum[k]; woff[k] = run; run += s; }
    }
    __syncthreads();
    int e = woff[w] + x - v;
    if (i < n) { offs[i] = e; cursor[i] = e; }
}

__global__ __launch_bounds__(256) void k_fill(const int* __restrict__ src_idx,
                                              const int* __restrict__ dst_idx,
                                              int* __restrict__ cursor,
                                              int* __restrict__ elist, int E) {
    int e = blockIdx.x * 256 + threadIdx.x;
    if (e < E) {
        int pos = atomicAdd(&cursor[dst_idx[e]], 1);
        elist[pos] = src_idx[e];
    }
}

// ---- fused GEMM + FiLM, 64 rows/block (round-2 known-good) ----
__device__ __forceinline__ bf16x8 load_frag(const unsigned short* p) {
    return *(const bf16x8*)p;
}
__device__ __forceinline__ bf16x8 load_frag(const float* p) {
    float4 u = ((const float4*)p)[0];
    float4 w = ((const float4*)p)[1];
    bf16x8 r;
    r[0] = (short)f2bf(u.x); r[1] = (short)f2bf(u.y);
    r[2] = (short)f2bf(u.z); r[3] = (short)f2bf(u.w);
    r[4] = (short)f2bf(w.x); r[5] = (short)f2bf(w.y);
    r[6] = (short)f2bf(w.z); r[7] = (short)f2bf(w.w);
    return r;
}

// Wc = [W(128); Fgamma(128); Fbeta(128)] x 128 bf16 row-major.
// Block: 4 waves, 64 rows (4 row-tiles). Wave w owns m col-tiles {2w,2w+1}.
template <typename XT>
__global__ __launch_bounds__(256, 2) void k_msg(const XT* __restrict__ X,
                                                const unsigned short* __restrict__ Wc,
                                                unsigned short* __restrict__ Msg, int n) {
    const int row0 = blockIdx.x << 6;
    const int wave = threadIdx.x >> 6;
    const int lane = threadIdx.x & 63;
    const int lr = lane & 15;
    const int quad = lane >> 4;

    bf16x8 a[4][4];   // [rowtile][kstep]
    #pragma unroll
    for (int rt = 0; rt < 4; rt++) {
        int r = row0 + rt * 16 + lr;
        if (r > n - 1) r = n - 1;
        const XT* xp = X + (size_t)r * IN_D + quad * 8;
        #pragma unroll
        for (int s = 0; s < 4; s++) a[rt][s] = load_frag(xp + 32 * s);
    }

    const int t0 = wave * 2;
    const int tidx[6] = {t0, t0 + 1, t0 + 8, t0 + 9, t0 + 16, t0 + 17};
    f32x4 acc[6][4];
    #pragma unroll
    for (int u = 0; u < 6; u++)
        #pragma unroll
        for (int rt = 0; rt < 4; rt++) acc[u][rt] = (f32x4){0.f, 0.f, 0.f, 0.f};

    #pragma unroll
    for (int s = 0; s < 4; s++) {
        #pragma unroll
        for (int u = 0; u < 6; u++) {
            const bf16x8 b = *(const bf16x8*)(Wc + (size_t)(16 * tidx[u] + lr) * IN_D + quad * 8 + 32 * s);
            #pragma unroll
            for (int rt = 0; rt < 4; rt++)
                acc[u][rt] = __builtin_amdgcn_mfma_f32_16x16x32_bf16(a[rt][s], b, acc[u][rt], 0, 0, 0);
        }
    }
    // FiLM: m=acc[0..1], gamma=acc[2..3], beta=acc[4..5]; identical (row,col) slots.
    #pragma unroll
    for (int u = 0; u < 2; u++) {
        #pragma unroll
        for (int rt = 0; rt < 4; rt++) {
            #pragma unroll
            for (int r = 0; r < 4; r++) {
                int row = row0 + rt * 16 + quad * 4 + r;
                if (row < n) {
                    float v = acc[2 + u][rt][r] * acc[u][rt][r] + acc[4 + u][rt][r];
                    v = v > 0.f ? v : 0.f;
                    Msg[(size_t)row * HID_D + 16 * (t0 + u) + lr] = f2bf(v);
                }
            }
        }
    }
}

// ---- CSR aggregate + fused LayerNorm (round-2 known-good loop) ----
// 1 wave/node; half-wave (32 lanes x uint2 = 256B) per edge; 2 edges/load-pair,
// x2 unrolled -> 4 gathers in flight. Optional fused projection epilogue.
template <bool FUSE_PROJ>
__global__ __launch_bounds__(256) void k_agg(const unsigned short* __restrict__ Msg,
                                             const int* __restrict__ elist,
                                             const int* __restrict__ offs,
                                             const float* __restrict__ gamma,
                                             const float* __restrict__ beta,
                                             unsigned short* __restrict__ Hout,
                                             const unsigned short* __restrict__ Wpb,
                                             const float* __restrict__ bp,
                                             float* __restrict__ out, int n) {
    __shared__ float hsh[4][128];
    const int wave = threadIdx.x >> 6;
    const int lane = threadIdx.x & 63;
    const int node = blockIdx.x * 4 + wave;
    if (node >= n) return;
    int half = lane >> 5;
    int l = lane & 31;
    int s0 = offs[node], s1 = offs[node + 1];
    float a0 = 0.f, a1 = 0.f, a2 = 0.f, a3 = 0.f;

#define ACC4(v) { a0 += bf2f((unsigned short)((v).x & 0xffffu)); \
                  a1 += bf2f((unsigned short)((v).x >> 16));     \
                  a2 += bf2f((unsigned short)((v).y & 0xffffu)); \
                  a3 += bf2f((unsigned short)((v).y >> 16)); }

    int i = s0;
    for (; i + 4 <= s1; i += 4) {
        int iA = elist[i + half];
        int iB = elist[i + 2 + half];
        uint2 vA = *(const uint2*)(Msg + (size_t)iA * HID_D + l * 4);
        uint2 vB = *(const uint2*)(Msg + (size_t)iB * HID_D + l * 4);
        ACC4(vA);
        ACC4(vB);
    }
    for (; i + 2 <= s1; i += 2) {
        int iA = elist[i + half];
        uint2 vA = *(const uint2*)(Msg + (size_t)iA * HID_D + l * 4);
        ACC4(vA);
    }
    if (i < s1 && half == 0) {
        int iA = elist[i];
        uint2 vA = *(const uint2*)(Msg + (size_t)iA * HID_D + l * 4);
        ACC4(vA);
    }
#undef ACC4

    // fold the two half-wave partial sums
    a0 += __shfl_xor(a0, 32);
    a1 += __shfl_xor(a1, 32);
    a2 += __shfl_xor(a2, 32);
    a3 += __shfl_xor(a3, 32);

    float s = a0 + a1 + a2 + a3;
    float sq = a0 * a0 + a1 * a1 + a2 * a2 + a3 * a3;
    #pragma unroll
    for (int d = 16; d; d >>= 1) {
        s += __shfl_xor(s, d);
        sq += __shfl_xor(sq, d);
    }
    float mu = s * (1.f / 128.f);
    float var = sq * (1.f / 128.f) - mu * mu;
    float rs = rsqrtf(var + 1e-5f);
    float4 g4 = ((const float4*)gamma)[l];
    float4 b4 = ((const float4*)beta)[l];
    float y0 = (a0 - mu) * rs * g4.x + b4.x;
    float y1 = (a1 - mu) * rs * g4.y + b4.y;
    float y2 = (a2 - mu) * rs * g4.z + b4.z;
    float y3 = (a3 - mu) * rs * g4.w + b4.w;

    if (!FUSE_PROJ) {
        if (half == 0) {
            uint2 o;
            o.x = (unsigned)f2bf(y0) | ((unsigned)f2bf(y1) << 16);
            o.y = (unsigned)f2bf(y2) | ((unsigned)f2bf(y3) << 16);
            *(uint2*)(Hout + (size_t)node * HID_D + l * 4) = o;
        }
    } else {
        // stash h in this wave's LDS slice, then lane j computes out col j
        if (half == 0) {
            *(float4*)&hsh[wave][l * 4] = (float4){y0, y1, y2, y3};
        }
        float accp = bp[lane];
        const unsigned short* wrow = Wpb + (size_t)lane * HID_D;
        #pragma unroll
        for (int c4 = 0; c4 < 32; c4++) {
            float4 hv = ((const float4*)hsh[wave])[c4];   // LDS broadcast
            ushort4 wv = ((const ushort4*)wrow)[c4];
            accp += hv.x * bf2f(wv.x) + hv.y * bf2f(wv.y) +
                    hv.z * bf2f(wv.z) + hv.w * bf2f(wv.w);
        }
        out[(size_t)node * OUT_D + lane] = 1.f / (1.f + __expf(-accp));
    }
}

extern "C" void kernel_launch(void* const* d_in, const int* in_sizes, int n_in,
                              void* d_out, int out_size, void* d_ws, size_t ws_size,
                              hipStream_t stream) {
    const float* features = (const float*)d_in[0];
    const int* src = (const int*)d_in[1];
    const int* dst = (const int*)d_in[2];
    const float* W1 = (const float*)d_in[3];
    const float* F1 = (const float*)d_in[4];
    const float* g1 = (const float*)d_in[5];
    const float* b1 = (const float*)d_in[6];
    const float* W2 = (const float*)d_in[7];
    const float* F2 = (const float*)d_in[8];
    const float* g2 = (const float*)d_in[9];
    const float* b2 = (const float*)d_in[10];
    const float* Wp = (const float*)d_in[11];
    const float* bp = (const float*)d_in[12];

    const int N = in_sizes[0] / IN_D;   // 50000
    const int E = in_sizes[1];          // 600000
    float* out = (float*)d_out;

    char* p = (char*)d_ws;
    auto alloc = [&](size_t b) -> char* {
        char* r = p;
        p += (b + 255) & ~(size_t)255;
        return r;
    };
    unsigned short* buf0 = (unsigned short*)alloc((size_t)N * HID_D * 2);
    unsigned short* buf1 = (unsigned short*)alloc((size_t)N * HID_D * 2);
    unsigned short* wc1  = (unsigned short*)alloc((size_t)3 * HID_D * IN_D * 2);
    unsigned short* wc2  = (unsigned short*)alloc((size_t)3 * HID_D * HID_D * 2);
    unsigned short* wpb  = (unsigned short*)alloc((size_t)OUT_D * HID_D * 2);
    int* deg    = (int*)alloc((size_t)N * 4);
    int* cursor = (int*)alloc((size_t)N * 4);
    int* offs   = (int*)alloc((size_t)(N + 1) * 4);
    int* elist  = (int*)alloc((size_t)E * 4);
    const int nb = (N + 255) / 256;     // 196
    int* part   = (int*)alloc((size_t)nb * 4);
    int* base   = (int*)alloc((size_t)nb * 4);

    const int eb = (E + 255) / 256;       // 2344 (also covers fused weight prep)
    const int mb = (N + 63) / 64;         // 782
    const int ab = (N + 3) / 4;           // 12500

    // CSR build: count(+prep) -> part -> mid -> scatter -> fill
    hipMemsetAsync(deg, 0, (size_t)N * 4, stream);
    k_count<<<eb, 256, 0, stream>>>(dst, deg, E, W1, F1, W2, F2, Wp, wc1, wc2, wpb);
    k_part<<<nb, 256, 0, stream>>>(deg, part, N);
    k_mid<<<1, 256, 0, stream>>>(part, base, offs, nb, N);
    k_scatter<<<nb, 256, 0, stream>>>(deg, base, offs, cursor, N);
    k_fill<<<eb, 256, 0, stream>>>(src, dst, cursor, elist, E);

    // layer 1 (reads fp32 features directly)
    k_msg<float><<<mb, 256, 0, stream>>>(features, wc1, buf1, N);
    k_agg<false><<<ab, 256, 0, stream>>>(buf1, elist, offs, g1, b1, buf0,
                                         nullptr, nullptr, nullptr, N);
    // layer 2 + fused projection/sigmoid
    k_msg<unsigned short><<<mb, 256, 0, stream>>>(buf0, wc2, buf1, N);
    k_agg<true><<<ab, 256, 0, stream>>>(buf1, elist, offs, g2, b2, nullptr,
                                        wpb, bp, out, N);
}

// Round 6
// 292.909 us; speedup vs baseline: 1.2538x; 1.2061x over previous
//
#include <hip/hip_runtime.h>
#include <hip/hip_bf16.h>
#include <math.h>

#define IN_D 128
#define HID_D 128
#define OUT_D 64

typedef __attribute__((ext_vector_type(8))) short bf16x8;
typedef __attribute__((ext_vector_type(4))) float f32x4;

__device__ __forceinline__ unsigned short f2bf(float f) {
    unsigned u = __float_as_uint(f);
    u += 0x7fffu + ((u >> 16) & 1u);   // RTNE
    return (unsigned short)(u >> 16);
}
__device__ __forceinline__ float bf2f(unsigned short h) {
    return __uint_as_float(((unsigned)h) << 16);
}

// ---- edge count + (fused, independent) weight prep fp32->bf16 ----
__global__ __launch_bounds__(256) void k_count(const int* __restrict__ dst_idx,
                                               int* __restrict__ deg, int E,
                                               const float* __restrict__ W1, const float* __restrict__ F1,
                                               const float* __restrict__ W2, const float* __restrict__ F2,
                                               const float* __restrict__ Wp,
                                               unsigned short* __restrict__ wc1,
                                               unsigned short* __restrict__ wc2,
                                               unsigned short* __restrict__ wpb) {
    int e = blockIdx.x * 256 + threadIdx.x;
    if (e < E) atomicAdd(&deg[dst_idx[e]], 1);
    const int NW = HID_D * IN_D;          // 16384
    const int NC = 3 * NW;                // 49152
    const int NP = OUT_D * HID_D;         // 8192
    int i = e;
    if (i < NC) {
        wc1[i] = f2bf(i < NW ? W1[i] : F1[i - NW]);
    } else if (i < 2 * NC) {
        int j = i - NC;
        wc2[j] = f2bf(j < NW ? W2[j] : F2[j - NW]);
    } else if (i < 2 * NC + NP) {
        int j = i - 2 * NC;
        wpb[j] = f2bf(Wp[j]);
    }
}

// ---- CSR build: 3-kernel prefix scan ----
__global__ __launch_bounds__(256) void k_part(const int* __restrict__ deg,
                                              int* __restrict__ part, int n) {
    int t = threadIdx.x, lane = t & 63, w = t >> 6;
    int i = blockIdx.x * 256 + t;
    int v = (i < n) ? deg[i] : 0;
    #pragma unroll
    for (int d = 32; d; d >>= 1) v += __shfl_xor(v, d);
    __shared__ int ws[4];
    if (lane == 0) ws[w] = v;
    __syncthreads();
    if (t == 0) part[blockIdx.x] = ws[0] + ws[1] + ws[2] + ws[3];
}

// single block, nb <= 256: exclusive scan of part -> base; total -> offs[n]
__global__ __launch_bounds__(256) void k_mid(const int* __restrict__ part,
                                             int* __restrict__ base,
                                             int* __restrict__ offs, int nb, int n) {
    int t = threadIdx.x, lane = t & 63, w = t >> 6;
    int v = (t < nb) ? part[t] : 0;
    int x = v;
    #pragma unroll
    for (int d = 1; d < 64; d <<= 1) {
        int y = __shfl_up(x, d);
        if (lane >= d) x += y;
    }
    __shared__ int wsum[4], woff[4];
    if (lane == 63) wsum[w] = x;
    __syncthreads();
    if (t == 0) {
        int run = 0;
        #pragma unroll
        for (int k = 0; k < 4; k++) { int s = wsum[k]; woff[k] = run; run += s; }
        offs[n] = run;
    }
    __syncthreads();
    if (t < nb) base[t] = woff[w] + x - v;
}

__global__ __launch_bounds__(256) void k_scatter(const int* __restrict__ deg,
                                                 const int* __restrict__ base,
                                                 int* __restrict__ offs,
                                                 int* __restrict__ cursor, int n) {
    int t = threadIdx.x, lane = t & 63, w = t >> 6;
    int i = blockIdx.x * 256 + t;
    int v = (i < n) ? deg[i] : 0;
    int x = v;
    #pragma unroll
    for (int d = 1; d < 64; d <<= 1) {
        int y = __shfl_up(x, d);
        if (lane >= d) x += y;
    }
    __shared__ int wsum[4], woff[4];
    if (lane == 63) wsum[w] = x;
    __syncthreads();
    if (t == 0) {
        int run = base[blockIdx.x];
        #pragma unroll
        for (int k = 0; k < 4; k++) { int s = wsum[k]; woff[k] = run; run += s; }
    }
    __syncthreads();
    int e = woff[w] + x - v;
    if (i < n) { offs[i] = e; cursor[i] = e; }
}

__global__ __launch_bounds__(256) void k_fill(const int* __restrict__ src_idx,
                                              const int* __restrict__ dst_idx,
                                              int* __restrict__ cursor,
                                              int* __restrict__ elist, int E) {
    int e = blockIdx.x * 256 + threadIdx.x;
    if (e < E) {
        int pos = atomicAdd(&cursor[dst_idx[e]], 1);
        elist[pos] = src_idx[e];
    }
}

// ---- fused GEMM + FiLM, 64 rows/block ----
__device__ __forceinline__ bf16x8 load_frag(const unsigned short* p) {
    return *(const bf16x8*)p;
}
__device__ __forceinline__ bf16x8 load_frag(const float* p) {
    float4 u = ((const float4*)p)[0];
    float4 w = ((const float4*)p)[1];
    bf16x8 r;
    r[0] = (short)f2bf(u.x); r[1] = (short)f2bf(u.y);
    r[2] = (short)f2bf(u.z); r[3] = (short)f2bf(u.w);
    r[4] = (short)f2bf(w.x); r[5] = (short)f2bf(w.y);
    r[6] = (short)f2bf(w.z); r[7] = (short)f2bf(w.w);
    return r;
}

// Wc = [W(128); Fgamma(128); Fbeta(128)] x 128 bf16 row-major.
// Block: 4 waves, 64 rows (4 row-tiles). Wave w owns m col-tiles {2w,2w+1}.
template <typename XT>
__global__ __launch_bounds__(256, 2) void k_msg(const XT* __restrict__ X,
                                                const unsigned short* __restrict__ Wc,
                                                unsigned short* __restrict__ Msg, int n) {
    const int row0 = blockIdx.x << 6;
    const int wave = threadIdx.x >> 6;
    const int lane = threadIdx.x & 63;
    const int lr = lane & 15;
    const int quad = lane >> 4;

    bf16x8 a[4][4];   // [rowtile][kstep]
    #pragma unroll
    for (int rt = 0; rt < 4; rt++) {
        int r = row0 + rt * 16 + lr;
        if (r > n - 1) r = n - 1;
        const XT* xp = X + (size_t)r * IN_D + quad * 8;
        #pragma unroll
        for (int s = 0; s < 4; s++) a[rt][s] = load_frag(xp + 32 * s);
    }

    const int t0 = wave * 2;
    const int tidx[6] = {t0, t0 + 1, t0 + 8, t0 + 9, t0 + 16, t0 + 17};
    f32x4 acc[6][4];
    #pragma unroll
    for (int u = 0; u < 6; u++)
        #pragma unroll
        for (int rt = 0; rt < 4; rt++) acc[u][rt] = (f32x4){0.f, 0.f, 0.f, 0.f};

    #pragma unroll
    for (int s = 0; s < 4; s++) {
        #pragma unroll
        for (int u = 0; u < 6; u++) {
            const bf16x8 b = *(const bf16x8*)(Wc + (size_t)(16 * tidx[u] + lr) * IN_D + quad * 8 + 32 * s);
            #pragma unroll
            for (int rt = 0; rt < 4; rt++)
                acc[u][rt] = __builtin_amdgcn_mfma_f32_16x16x32_bf16(a[rt][s], b, acc[u][rt], 0, 0, 0);
        }
    }
    // FiLM: m=acc[0..1], gamma=acc[2..3], beta=acc[4..5]; identical (row,col) slots.
    #pragma unroll
    for (int u = 0; u < 2; u++) {
        #pragma unroll
        for (int rt = 0; rt < 4; rt++) {
            #pragma unroll
            for (int r = 0; r < 4; r++) {
                int row = row0 + rt * 16 + quad * 4 + r;
                if (row < n) {
                    float v = acc[2 + u][rt][r] * acc[u][rt][r] + acc[4 + u][rt][r];
                    v = v > 0.f ? v : 0.f;
                    Msg[(size_t)row * HID_D + 16 * (t0 + u) + lr] = f2bf(v);
                }
            }
        }
    }
}

// ---- CSR aggregate + fused LayerNorm (round-2 known-good, no proj fusion) ----
// 1 wave/node; half-wave (32 lanes x uint2 = 256B) per edge; x2 unroll -> 4 in flight.
__global__ __launch_bounds__(256) void k_agg_ln(const unsigned short* __restrict__ Msg,
                                                const int* __restrict__ elist,
                                                const int* __restrict__ offs,
                                                const float* __restrict__ gamma,
                                                const float* __restrict__ beta,
                                                unsigned short* __restrict__ Hout, int n) {
    int node = blockIdx.x * 4 + (threadIdx.x >> 6);
    int lane = threadIdx.x & 63;
    int half = lane >> 5;
    int l = lane & 31;
    if (node >= n) return;
    int s0 = offs[node], s1 = offs[node + 1];
    float a0 = 0.f, a1 = 0.f, a2 = 0.f, a3 = 0.f;

#define ACC4(v) { a0 += bf2f((unsigned short)((v).x & 0xffffu)); \
                  a1 += bf2f((unsigned short)((v).x >> 16));     \
                  a2 += bf2f((unsigned short)((v).y & 0xffffu)); \
                  a3 += bf2f((unsigned short)((v).y >> 16)); }

    int i = s0;
    for (; i + 4 <= s1; i += 4) {
        int iA = elist[i + half];
        int iB = elist[i + 2 + half];
        uint2 vA = *(const uint2*)(Msg + (size_t)iA * HID_D + l * 4);
        uint2 vB = *(const uint2*)(Msg + (size_t)iB * HID_D + l * 4);
        ACC4(vA);
        ACC4(vB);
    }
    for (; i + 2 <= s1; i += 2) {
        int iA = elist[i + half];
        uint2 vA = *(const uint2*)(Msg + (size_t)iA * HID_D + l * 4);
        ACC4(vA);
    }
    if (i < s1 && half == 0) {
        int iA = elist[i];
        uint2 vA = *(const uint2*)(Msg + (size_t)iA * HID_D + l * 4);
        ACC4(vA);
    }
#undef ACC4

    // fold the two half-wave partial sums
    a0 += __shfl_xor(a0, 32);
    a1 += __shfl_xor(a1, 32);
    a2 += __shfl_xor(a2, 32);
    a3 += __shfl_xor(a3, 32);

    float s = a0 + a1 + a2 + a3;
    float sq = a0 * a0 + a1 * a1 + a2 * a2 + a3 * a3;
    #pragma unroll
    for (int d = 16; d; d >>= 1) {
        s += __shfl_xor(s, d);
        sq += __shfl_xor(sq, d);
    }
    float mu = s * (1.f / 128.f);
    float var = sq * (1.f / 128.f) - mu * mu;
    float rs = rsqrtf(var + 1e-5f);
    float4 g4 = ((const float4*)gamma)[l];
    float4 b4 = ((const float4*)beta)[l];
    float y0 = (a0 - mu) * rs * g4.x + b4.x;
    float y1 = (a1 - mu) * rs * g4.y + b4.y;
    float y2 = (a2 - mu) * rs * g4.z + b4.z;
    float y3 = (a3 - mu) * rs * g4.w + b4.w;
    if (half == 0) {
        uint2 o;
        o.x = (unsigned)f2bf(y0) | ((unsigned)f2bf(y1) << 16);
        o.y = (unsigned)f2bf(y2) | ((unsigned)f2bf(y3) << 16);
        *(uint2*)(Hout + (size_t)node * HID_D + l * 4) = o;
    }
}

// ---- projection: out = sigmoid(h @ Wp^T + bp), 64 rows/block, wave w = col-tile w ----
__global__ __launch_bounds__(256) void k_proj(const unsigned short* __restrict__ H,
                                              const unsigned short* __restrict__ Wpb,
                                              const float* __restrict__ bp,
                                              float* __restrict__ out, int n) {
    const int row0 = blockIdx.x << 6;
    const int wave = threadIdx.x >> 6;
    const int lane = threadIdx.x & 63;
    const int lr = lane & 15;
    const int quad = lane >> 4;

    f32x4 acc[4];
    #pragma unroll
    for (int rt = 0; rt < 4; rt++) acc[rt] = (f32x4){0.f, 0.f, 0.f, 0.f};

    #pragma unroll
    for (int s = 0; s < 4; s++) {
        bf16x8 bv = *(const bf16x8*)(Wpb + (size_t)(16 * wave + lr) * HID_D + quad * 8 + 32 * s);
        #pragma unroll
        for (int rt = 0; rt < 4; rt++) {
            int r = row0 + rt * 16 + lr;
            if (r > n - 1) r = n - 1;
            bf16x8 av = *(const bf16x8*)(H + (size_t)r * HID_D + quad * 8 + 32 * s);
            acc[rt] = __builtin_amdgcn_mfma_f32_16x16x32_bf16(av, bv, acc[rt], 0, 0, 0);
        }
    }
    float bias = bp[16 * wave + lr];
    #pragma unroll
    for (int rt = 0; rt < 4; rt++) {
        #pragma unroll
        for (int r = 0; r < 4; r++) {
            int row = row0 + rt * 16 + quad * 4 + r;
            if (row < n) {
                float z = acc[rt][r] + bias;
                out[(size_t)row * OUT_D + 16 * wave + lr] = 1.f / (1.f + __expf(-z));
            }
        }
    }
}

extern "C" void kernel_launch(void* const* d_in, const int* in_sizes, int n_in,
                              void* d_out, int out_size, void* d_ws, size_t ws_size,
                              hipStream_t stream) {
    const float* features = (const float*)d_in[0];
    const int* src = (const int*)d_in[1];
    const int* dst = (const int*)d_in[2];
    const float* W1 = (const float*)d_in[3];
    const float* F1 = (const float*)d_in[4];
    const float* g1 = (const float*)d_in[5];
    const float* b1 = (const float*)d_in[6];
    const float* W2 = (const float*)d_in[7];
    const float* F2 = (const float*)d_in[8];
    const float* g2 = (const float*)d_in[9];
    const float* b2 = (const float*)d_in[10];
    const float* Wp = (const float*)d_in[11];
    const float* bp = (const float*)d_in[12];

    const int N = in_sizes[0] / IN_D;   // 50000
    const int E = in_sizes[1];          // 600000
    float* out = (float*)d_out;

    char* p = (char*)d_ws;
    auto alloc = [&](size_t b) -> char* {
        char* r = p;
        p += (b + 255) & ~(size_t)255;
        return r;
    };
    unsigned short* buf0 = (unsigned short*)alloc((size_t)N * HID_D * 2);
    unsigned short* buf1 = (unsigned short*)alloc((size_t)N * HID_D * 2);
    unsigned short* wc1  = (unsigned short*)alloc((size_t)3 * HID_D * IN_D * 2);
    unsigned short* wc2  = (unsigned short*)alloc((size_t)3 * HID_D * HID_D * 2);
    unsigned short* wpb  = (unsigned short*)alloc((size_t)OUT_D * HID_D * 2);
    int* deg    = (int*)alloc((size_t)N * 4);
    int* cursor = (int*)alloc((size_t)N * 4);
    int* offs   = (int*)alloc((size_t)(N + 1) * 4);
    int* elist  = (int*)alloc((size_t)E * 4);
    const int nb = (N + 255) / 256;     // 196
    int* part   = (int*)alloc((size_t)nb * 4);
    int* base   = (int*)alloc((size_t)nb * 4);

    const int eb = (E + 255) / 256;       // 2344 (also covers fused weight prep)
    const int mb = (N + 63) / 64;         // 782
    const int ab = (N + 3) / 4;           // 12500

    // CSR build: count(+prep) -> part -> mid -> scatter -> fill
    hipMemsetAsync(deg, 0, (size_t)N * 4, stream);
    k_count<<<eb, 256, 0, stream>>>(dst, deg, E, W1, F1, W2, F2, Wp, wc1, wc2, wpb);
    k_part<<<nb, 256, 0, stream>>>(deg, part, N);
    k_mid<<<1, 256, 0, stream>>>(part, base, offs, nb, N);
    k_scatter<<<nb, 256, 0, stream>>>(deg, base, offs, cursor, N);
    k_fill<<<eb, 256, 0, stream>>>(src, dst, cursor, elist, E);

    // layer 1 (reads fp32 features directly)
    k_msg<float><<<mb, 256, 0, stream>>>(features, wc1, buf1, N);
    k_agg_ln<<<ab, 256, 0, stream>>>(buf1, elist, offs, g1, b1, buf0, N);
    // layer 2
    k_msg<unsigned short><<<mb, 256, 0, stream>>>(buf0, wc2, buf1, N);
    k_agg_ln<<<ab, 256, 0, stream>>>(buf1, elist, offs, g2, b2, buf0, N);
    // projection + sigmoid
    k_proj<<<mb, 256, 0, stream>>>(buf0, wpb, bp, out, N);
}